// Round 11
// baseline (203.055 us; speedup 1.0000x reference)
//
#include <hip/hip_runtime.h>
#include <hip/hip_bf16.h>
#include <math.h>

#define NN 6144
#define DD 128
#define NCLS 20
#define NBATCH 5
#define NB 48                      // 6144 / 128 tile blocks per dim
#define NPAIR (NB * (NB + 1) / 2)  // 1176 upper-tri tile pairs

typedef float f32x4 __attribute__((ext_vector_type(4)));
typedef short bf16x8 __attribute__((ext_vector_type(8)));

// ws float layout:
//   ushort xnb[NN*DD]        bytes [0, 1572864)  normalized rows, bf16
//   float  diag[NN]          float idx DOFF: s_ii = sum of bf16(xn)^2
//   float  strips[NB][NN][4] float idx STOFF: per-(tile-strip) stats, no atomics
//   float  acc[50]           float idx AOFF
//   int    counter           float idx COFF
#define SOFF (NN * DD / 2)
#define DOFF SOFF
#define STOFF (DOFF + NN)
#define AOFF (STOFF + NB * NN * 4)
#define COFF (AOFF + 50)

// normalize rows -> bf16, compute diag s_ii; block 24 zeroes acc+counter.
__global__ __launch_bounds__(256) void k_prep(const float* __restrict__ x,
                                              float* __restrict__ ws) {
    const int t = threadIdx.x;
    if (blockIdx.x == 24 && t < 51) ws[AOFF + t] = 0.0f;  // acc[50] + counter
    const int lane = t & 63;
    const int row = blockIdx.x * 4 + (t >> 6);
    float2 v = *(const float2*)(x + row * DD + 2 * lane);
    float s = v.x * v.x + v.y * v.y;
#pragma unroll
    for (int m = 1; m < 64; m <<= 1) s += __shfl_xor(s, m, 64);
    float rinv = 1.0f / fmaxf(sqrtf(s), 1e-8f);
    __hip_bfloat16 h0 = __float2bfloat16(v.x * rinv);
    __hip_bfloat16 h1 = __float2bfloat16(v.y * rinv);
    // exact bf16 self-dot (matches MFMA's fp32-of-bf16 products)
    float f0 = __bfloat162float(h0), f1 = __bfloat162float(h1);
    float s2 = f0 * f0 + f1 * f1;
#pragma unroll
    for (int m = 1; m < 64; m <<= 1) s2 += __shfl_xor(s2, m, 64);
    if (lane == 0) ws[DOFF + row] = s2;
    ushort2 u;
    u.x = *(ushort*)&h0;
    u.y = *(ushort*)&h1;
    ushort* xnb = (ushort*)ws;
    *(ushort2*)(xnb + row * DD + 2 * lane) = u;
}

// owner-scatter reductions, scalar-expanded (SROA-friendly)
#define RED16(v)                                                      \
    {                                                                 \
        float s0 = up3 ? v[0] : v[2], k0 = up3 ? v[2] : v[0];         \
        float s1 = up3 ? v[1] : v[3], k1 = up3 ? v[3] : v[1];         \
        v[0] = k0 + __shfl_xor(s0, 8, 64);                            \
        v[1] = k1 + __shfl_xor(s1, 8, 64);                            \
        float s2 = up2 ? v[0] : v[1], k2 = up2 ? v[1] : v[0];         \
        v[0] = k2 + __shfl_xor(s2, 4, 64);                            \
        v[0] += __shfl_xor(v[0], 2, 64);                              \
        v[0] += __shfl_xor(v[0], 1, 64);                              \
    }

#define RED4(v)                                                       \
    {                                                                 \
        float s0 = q1 ? v[0] : v[2], k0 = q1 ? v[2] : v[0];           \
        float s1 = q1 ? v[1] : v[3], k1 = q1 ? v[3] : v[1];           \
        v[0] = k0 + __shfl_xor(s0, 32, 64);                           \
        v[1] = k1 + __shfl_xor(s1, 32, 64);                           \
        float s2 = q0 ? v[0] : v[1], k2 = q0 ? v[1] : v[0];           \
        v[0] = k2 + __shfl_xor(s2, 16, 64);                           \
    }

// 128x128 tile per block, upper-tri pairs. Pitch 72 (144 B, 16B-aligned).
// Unified epilogue (self-term corrected later); strip stores, no atomics.
__global__ __launch_bounds__(256, 4) void k_main(const float* __restrict__ temp,
                                                 const int* __restrict__ tg,
                                                 const int* __restrict__ bt,
                                                 float* __restrict__ ws) {
    __shared__ __align__(16) char smem[36864];  // 2 tiles of 128x72 ushort
    __shared__ int tgA[128], btA[128], tgB[128], btB[128];  // 2048 B

    ushort (*tA)[72] = (ushort(*)[72])smem;              // 18432 B
    ushort (*tB)[72] = (ushort(*)[72])(smem + 18432);    // 18432 B
    float* sRowF = (float*)smem;            // alias: [2][4][128] = 4096 B
    float* sColF = (float*)(smem + 4096);   // alias: [2][4][128] = 4096 B

    const ushort* xnb = (const ushort*)ws;
    float* strips = ws + STOFF;

    int bi = 0, rem = blockIdx.x;
    while (rem >= NB - bi) { rem -= NB - bi; ++bi; }
    const int bj = bi + rem;
    const int I = bi * 128, J = bj * 128;
    const bool isDiag = (bi == bj);

    const int t = threadIdx.x;
    const int w = t >> 6;
    const int lane = t & 63;
    const int tx16 = lane & 15;
    const int quad = lane >> 4;
    const int rowBase = (w >> 1) * 64;
    const int colBase = (w & 1) * 64;

    const float tc = fminf(fmaxf(temp[0], 0.1f), 1.0f);
    const float c1 = 1.4426950408889634f / tc;   // exp(s/t)   = 2^(s*c1)
    const float c2 = 2.8853900817779268f;        // exp(s/0.5) = 2^(s*c2)

    if (t < 128) { tgA[t] = tg[I + t]; btA[t] = bt[I + t]; }
    else { int u2 = t - 128; tgB[u2] = tg[J + u2]; btB[u2] = bt[J + u2]; }

    f32x4 acc[4][4];
#pragma unroll
    for (int mt = 0; mt < 4; ++mt)
#pragma unroll
        for (int nt = 0; nt < 4; ++nt) acc[mt][nt] = (f32x4){0.f, 0.f, 0.f, 0.f};

    for (int kc = 0; kc < 2; ++kc) {
        if (kc) __syncthreads();
        {   // stage 128 rows x 64 bf16 for both tiles (16B-aligned)
            const int r0 = t >> 3, ch = t & 7;
            const ushort* gA = xnb + (I + r0) * DD + kc * 64 + ch * 8;
            const ushort* gB = xnb + (J + r0) * DD + kc * 64 + ch * 8;
#pragma unroll
            for (int it = 0; it < 4; ++it) {
                *(float4*)&tA[r0 + 32 * it][ch * 8] = *(const float4*)(gA + 32 * it * DD);
                *(float4*)&tB[r0 + 32 * it][ch * 8] = *(const float4*)(gB + 32 * it * DD);
            }
        }
        __syncthreads();
#pragma unroll
        for (int ks = 0; ks < 2; ++ks) {
            bf16x8 a[4], b[4];
            const int ko = ks * 32 + quad * 8;
#pragma unroll
            for (int mt = 0; mt < 4; ++mt)
                a[mt] = *(const bf16x8*)&tA[rowBase + 16 * mt + tx16][ko];
#pragma unroll
            for (int nt = 0; nt < 4; ++nt)
                b[nt] = *(const bf16x8*)&tB[colBase + 16 * nt + tx16][ko];
#pragma unroll
            for (int mt = 0; mt < 4; ++mt)
#pragma unroll
                for (int nt = 0; nt < 4; ++nt)
                    acc[mt][nt] = __builtin_amdgcn_mfma_f32_16x16x32_bf16(
                        a[mt], b[nt], acc[mt][nt], 0, 0, 0);
        }
    }

    // tiles dead from here; stats alias onto the same LDS
    __syncthreads();

    float cPT[4] = {0}, cTT[4] = {0}, cPB[4] = {0}, cTB[4] = {0};
    int tjv[4], bjv[4];
#pragma unroll
    for (int nt = 0; nt < 4; ++nt) {
        int jl = colBase + 16 * nt + tx16;
        tjv[nt] = tgB[jl];
        bjv[nt] = btB[jl];
    }
    const bool up3 = (tx16 >> 3) & 1;
    const bool up2 = (tx16 >> 2) & 1;
    const int pOwn = tx16 >> 2;

#pragma unroll
    for (int mt = 0; mt < 4; ++mt) {
        float rPT[4] = {0}, rTT[4] = {0}, rPB[4] = {0}, rTB[4] = {0};
        int til[4], bil[4];
#pragma unroll
        for (int p = 0; p < 4; ++p) {
            int il = rowBase + 16 * mt + 4 * quad + p;
            til[p] = tgA[il];
            bil[p] = btA[il];
        }
#pragma unroll
        for (int nt = 0; nt < 4; ++nt) {
#pragma unroll
            for (int p = 0; p < 4; ++p) {
                float s = acc[mt][nt][p];
                float et = __builtin_amdgcn_exp2f(c1 * s);
                float eb = __builtin_amdgcn_exp2f(c2 * s);
                bool st = (til[p] == tjv[nt]);
                bool sb = (bil[p] == bjv[nt]);
                float etp = st ? et : 0.f;
                float ebp = st ? eb : 0.f;
                float ebb = (st && sb) ? eb : 0.f;
                rTT[p] += et;
                rPT[p] += etp;
                rTB[p] += ebp;
                rPB[p] += ebb;
                cTT[nt] += et;
                cPT[nt] += etp;
                cTB[nt] += ebp;
                cPB[nt] += ebb;
            }
        }
        RED16(rPT);
        RED16(rTT);
        RED16(rPB);
        RED16(rTB);
        if ((tx16 & 3) == 0) {
            int il = rowBase + 16 * mt + 4 * quad + pOwn;
            int rep = (w & 1) * 512;
            sRowF[rep + 0 * 128 + il] = rPT[0];
            sRowF[rep + 1 * 128 + il] = rTT[0];
            sRowF[rep + 2 * 128 + il] = rPB[0];
            sRowF[rep + 3 * 128 + il] = rTB[0];
        }
    }
    if (!isDiag) {
        const bool q1 = (quad >> 1) & 1;
        const bool q0 = quad & 1;
        RED4(cPT);
        RED4(cTT);
        RED4(cPB);
        RED4(cTB);
        int cl = colBase + 16 * quad + tx16;
        int rep = (w >> 1) * 512;
        sColF[rep + 0 * 128 + cl] = cPT[0];
        sColF[rep + 1 * 128 + cl] = cTT[0];
        sColF[rep + 2 * 128 + cl] = cPB[0];
        sColF[rep + 3 * 128 + cl] = cTB[0];
    }

    // coalesced strip flush (float4 stores, no atomics; disjoint by construction)
    __syncthreads();
    if (t < 128) {
        float4 v;
        v.x = sRowF[0 * 128 + t] + sRowF[512 + 0 * 128 + t];
        v.y = sRowF[1 * 128 + t] + sRowF[512 + 1 * 128 + t];
        v.z = sRowF[2 * 128 + t] + sRowF[512 + 2 * 128 + t];
        v.w = sRowF[3 * 128 + t] + sRowF[512 + 3 * 128 + t];
        *(float4*)&strips[(size_t)(bj * NN + I + t) * 4] = v;
    } else if (!isDiag) {
        int u2 = t - 128;
        float4 v;
        v.x = sColF[0 * 128 + u2] + sColF[512 + 0 * 128 + u2];
        v.y = sColF[1 * 128 + u2] + sColF[512 + 1 * 128 + u2];
        v.z = sColF[2 * 128 + u2] + sColF[512 + 2 * 128 + u2];
        v.w = sColF[3 * 128 + u2] + sColF[512 + 3 * 128 + u2];
        *(float4*)&strips[(size_t)(bi * NN + J + u2) * 4] = v;
    }
}

// 24 blocks: strip reduce + diag correction + per-row losses + per-wave accum +
// global acc atomics + last-block final weighted sum.
__global__ __launch_bounds__(256) void k_fin(const float* __restrict__ temp,
                                             const int* __restrict__ tg,
                                             const int* __restrict__ bt,
                                             const float* __restrict__ wt,
                                             const float* __restrict__ wb,
                                             float* __restrict__ ws,
                                             float* __restrict__ out) {
    __shared__ int hh[NCLS + NCLS * NBATCH];
    __shared__ float ph[4][52];
    __shared__ int lastFlag;
    const int t = threadIdx.x;
    const int wv = t >> 6;
    if (t < NCLS + NCLS * NBATCH) hh[t] = 0;
    if (t < 52 * 4) ((float*)ph)[t] = 0.0f;
    __syncthreads();
    for (int i = t; i < NN; i += 256) {
        int c = tg[i], b = bt[i];
        atomicAdd(&hh[c], 1);
        atomicAdd(&hh[NCLS + c * NBATCH + b], 1);
    }
    __syncthreads();
    const float* strips = ws + STOFF;
    const float tc = fminf(fmaxf(temp[0], 0.1f), 1.0f);
    const float c1 = 1.4426950408889634f / tc;
    const float c2 = 2.8853900817779268f;
    {
        const int i = blockIdx.x * 256 + t;
        float pt = 0.f, tt = 0.f, pb = 0.f, tb = 0.f;
#pragma unroll 8
        for (int s = 0; s < NB; ++s) {
            float4 v = *(const float4*)&strips[(size_t)(s * NN + i) * 4];
            pt += v.x;
            tt += v.y;
            pb += v.z;
            tb += v.w;
        }
        // subtract self term (diag tiles were accumulated without exclusion)
        float s2 = ws[DOFF + i];
        float e1 = __builtin_amdgcn_exp2f(c1 * s2);
        float e2 = __builtin_amdgcn_exp2f(c2 * s2);
        pt -= e1;
        tt -= e1;
        pb -= e2;
        tb -= e2;
        int ti = tg[i], bi = bt[i];
        int cp = hh[ti];
        int cpb = hh[NCLS + ti * NBATCH + bi];
        if (cp >= 2 && (NN - cp) >= 1) {
            float loss = logf(tt / pt);  // -log(pos/tot)
            atomicAdd(&ph[wv][ti], loss);
            atomicAdd(&ph[wv][20 + ti], 1.0f);
        }
        if (cpb >= 2 && (cp - cpb) >= 1) {
            float lb = logf(tb / pb);
            atomicAdd(&ph[wv][40 + bi], 1.0f / lb);
            atomicAdd(&ph[wv][45 + bi], 1.0f);
        }
    }
    __syncthreads();
    if (t < 50) {
        float s = ph[0][t] + ph[1][t] + ph[2][t] + ph[3][t];
        atomicAdd(&ws[AOFF + t], s);
    }
    __syncthreads();
    if (t == 0) {
        __threadfence();
        lastFlag = (atomicAdd((int*)(ws + COFF), 1) == 23) ? 1 : 0;
    }
    __syncthreads();
    if (lastFlag) {
        __threadfence();
        if (t < 64) {
            const float* acc = ws + AOFF;
            float term = 0.0f;
            if (t < NCLS) {
                float cnt = acc[NCLS + t];
                if (cnt > 0.f) term = 0.9f * (acc[t] / cnt) * wt[t];
            } else if (t >= 32 && t < 32 + NBATCH) {
                int b = t - 32;
                float cnt = acc[2 * NCLS + NBATCH + b];
                if (cnt > 0.f) term = 0.1f * (acc[2 * NCLS + b] / cnt) * wb[b];
            }
#pragma unroll
            for (int m = 1; m < 64; m <<= 1) term += __shfl_xor(term, m, 64);
            if (t == 0) out[0] = term;
        }
    }
}

extern "C" void kernel_launch(void* const* d_in, const int* in_sizes, int n_in,
                              void* d_out, int out_size, void* d_ws, size_t ws_size,
                              hipStream_t stream) {
    const float* x    = (const float*)d_in[0];
    const float* temp = (const float*)d_in[1];
    const float* wt   = (const float*)d_in[2];
    const float* wb   = (const float*)d_in[3];
    const int*   tg   = (const int*)d_in[4];
    const int*   bt   = (const int*)d_in[5];
    float* out = (float*)d_out;
    float* ws = (float*)d_ws;

    k_prep<<<NN / 4, 256, 0, stream>>>(x, ws);
    k_main<<<NPAIR, 256, 0, stream>>>(temp, tg, bt, ws);
    k_fin<<<24, 256, 0, stream>>>(temp, tg, bt, wt, wb, ws, out);
}

// Round 12
// 115.896 us; speedup vs baseline: 1.7520x; 1.7520x over previous
//
#include <hip/hip_runtime.h>
#include <hip/hip_bf16.h>
#include <math.h>

#define NN 6144
#define DD 128
#define NCLS 20
#define NBATCH 5
#define NB 48                      // 6144 / 128 tile blocks per dim
#define NPAIR (NB * (NB + 1) / 2)  // 1176 upper-tri tile pairs

typedef float f32x4 __attribute__((ext_vector_type(4)));
typedef short bf16x8 __attribute__((ext_vector_type(8)));

// ws float layout:
//   ushort xnb[NN*DD]        bytes [0, 1572864)  normalized rows, bf16
//   float  diag[NN]          float idx DOFF: s_ii = sum of bf16(xn)^2
//   float  strips[NB][NN][4] float idx STOFF: per-(tile-strip) stats, no atomics
//   float  acc[50]           float idx AOFF
//   int    counter           float idx COFF
#define SOFF (NN * DD / 2)
#define DOFF SOFF
#define STOFF (DOFF + NN)
#define AOFF (STOFF + NB * NN * 4)
#define COFF (AOFF + 50)

// normalize rows -> bf16, compute diag s_ii; block 24 zeroes acc+counter.
__global__ __launch_bounds__(256) void k_prep(const float* __restrict__ x,
                                              float* __restrict__ ws) {
    const int t = threadIdx.x;
    if (blockIdx.x == 24 && t < 51) ws[AOFF + t] = 0.0f;  // acc[50] + counter
    const int lane = t & 63;
    const int row = blockIdx.x * 4 + (t >> 6);
    float2 v = *(const float2*)(x + row * DD + 2 * lane);
    float s = v.x * v.x + v.y * v.y;
#pragma unroll
    for (int m = 1; m < 64; m <<= 1) s += __shfl_xor(s, m, 64);
    float rinv = 1.0f / fmaxf(sqrtf(s), 1e-8f);
    __hip_bfloat16 h0 = __float2bfloat16(v.x * rinv);
    __hip_bfloat16 h1 = __float2bfloat16(v.y * rinv);
    // exact bf16 self-dot (matches MFMA's fp32-of-bf16 products)
    float f0 = __bfloat162float(h0), f1 = __bfloat162float(h1);
    float s2 = f0 * f0 + f1 * f1;
#pragma unroll
    for (int m = 1; m < 64; m <<= 1) s2 += __shfl_xor(s2, m, 64);
    if (lane == 0) ws[DOFF + row] = s2;
    ushort2 u;
    u.x = *(ushort*)&h0;
    u.y = *(ushort*)&h1;
    ushort* xnb = (ushort*)ws;
    *(ushort2*)(xnb + row * DD + 2 * lane) = u;
}

// owner-scatter reductions, scalar-expanded (SROA-friendly)
#define RED16(v)                                                      \
    {                                                                 \
        float s0 = up3 ? v[0] : v[2], k0 = up3 ? v[2] : v[0];         \
        float s1 = up3 ? v[1] : v[3], k1 = up3 ? v[3] : v[1];         \
        v[0] = k0 + __shfl_xor(s0, 8, 64);                            \
        v[1] = k1 + __shfl_xor(s1, 8, 64);                            \
        float s2 = up2 ? v[0] : v[1], k2 = up2 ? v[1] : v[0];         \
        v[0] = k2 + __shfl_xor(s2, 4, 64);                            \
        v[0] += __shfl_xor(v[0], 2, 64);                              \
        v[0] += __shfl_xor(v[0], 1, 64);                              \
    }

#define RED4(v)                                                       \
    {                                                                 \
        float s0 = q1 ? v[0] : v[2], k0 = q1 ? v[2] : v[0];           \
        float s1 = q1 ? v[1] : v[3], k1 = q1 ? v[3] : v[1];           \
        v[0] = k0 + __shfl_xor(s0, 32, 64);                           \
        v[1] = k1 + __shfl_xor(s1, 32, 64);                           \
        float s2 = q0 ? v[0] : v[1], k2 = q0 ? v[1] : v[0];           \
        v[0] = k2 + __shfl_xor(s2, 16, 64);                           \
    }

// 128x128 tile per block, upper-tri pairs. Pitch 72 (144 B, 16B-aligned).
// Unified epilogue (self-term corrected in k_fin); strip stores, no atomics.
// NOTE: no min-waves launch_bounds — (256,4) clamped VGPR to 64 and spilled
// ~190 MB/dispatch to scratch (round 11). Natural allocation is 112 VGPR.
__global__ __launch_bounds__(256) void k_main(const float* __restrict__ temp,
                                              const int* __restrict__ tg,
                                              const int* __restrict__ bt,
                                              float* __restrict__ ws) {
    __shared__ __align__(16) char smem[36864];  // 2 tiles of 128x72 ushort
    __shared__ int tgA[128], btA[128], tgB[128], btB[128];  // 2048 B

    ushort (*tA)[72] = (ushort(*)[72])smem;              // 18432 B
    ushort (*tB)[72] = (ushort(*)[72])(smem + 18432);    // 18432 B
    float* sRowF = (float*)smem;            // alias: [2][4][128] = 4096 B
    float* sColF = (float*)(smem + 4096);   // alias: [2][4][128] = 4096 B

    const ushort* xnb = (const ushort*)ws;
    float* strips = ws + STOFF;

    int bi = 0, rem = blockIdx.x;
    while (rem >= NB - bi) { rem -= NB - bi; ++bi; }
    const int bj = bi + rem;
    const int I = bi * 128, J = bj * 128;
    const bool isDiag = (bi == bj);

    const int t = threadIdx.x;
    const int w = t >> 6;
    const int lane = t & 63;
    const int tx16 = lane & 15;
    const int quad = lane >> 4;
    const int rowBase = (w >> 1) * 64;
    const int colBase = (w & 1) * 64;

    const float tc = fminf(fmaxf(temp[0], 0.1f), 1.0f);
    const float c1 = 1.4426950408889634f / tc;   // exp(s/t)   = 2^(s*c1)
    const float c2 = 2.8853900817779268f;        // exp(s/0.5) = 2^(s*c2)

    if (t < 128) { tgA[t] = tg[I + t]; btA[t] = bt[I + t]; }
    else { int u2 = t - 128; tgB[u2] = tg[J + u2]; btB[u2] = bt[J + u2]; }

    f32x4 acc[4][4];
#pragma unroll
    for (int mt = 0; mt < 4; ++mt)
#pragma unroll
        for (int nt = 0; nt < 4; ++nt) acc[mt][nt] = (f32x4){0.f, 0.f, 0.f, 0.f};

    for (int kc = 0; kc < 2; ++kc) {
        if (kc) __syncthreads();
        {   // stage 128 rows x 64 bf16 for both tiles (16B-aligned)
            const int r0 = t >> 3, ch = t & 7;
            const ushort* gA = xnb + (I + r0) * DD + kc * 64 + ch * 8;
            const ushort* gB = xnb + (J + r0) * DD + kc * 64 + ch * 8;
#pragma unroll
            for (int it = 0; it < 4; ++it) {
                *(float4*)&tA[r0 + 32 * it][ch * 8] = *(const float4*)(gA + 32 * it * DD);
                *(float4*)&tB[r0 + 32 * it][ch * 8] = *(const float4*)(gB + 32 * it * DD);
            }
        }
        __syncthreads();
#pragma unroll
        for (int ks = 0; ks < 2; ++ks) {
            bf16x8 a[4], b[4];
            const int ko = ks * 32 + quad * 8;
#pragma unroll
            for (int mt = 0; mt < 4; ++mt)
                a[mt] = *(const bf16x8*)&tA[rowBase + 16 * mt + tx16][ko];
#pragma unroll
            for (int nt = 0; nt < 4; ++nt)
                b[nt] = *(const bf16x8*)&tB[colBase + 16 * nt + tx16][ko];
#pragma unroll
            for (int mt = 0; mt < 4; ++mt)
#pragma unroll
                for (int nt = 0; nt < 4; ++nt)
                    acc[mt][nt] = __builtin_amdgcn_mfma_f32_16x16x32_bf16(
                        a[mt], b[nt], acc[mt][nt], 0, 0, 0);
        }
    }

    // tiles dead from here; stats alias onto the same LDS
    __syncthreads();

    float cPT[4] = {0}, cTT[4] = {0}, cPB[4] = {0}, cTB[4] = {0};
    int tjv[4], bjv[4];
#pragma unroll
    for (int nt = 0; nt < 4; ++nt) {
        int jl = colBase + 16 * nt + tx16;
        tjv[nt] = tgB[jl];
        bjv[nt] = btB[jl];
    }
    const bool up3 = (tx16 >> 3) & 1;
    const bool up2 = (tx16 >> 2) & 1;
    const int pOwn = tx16 >> 2;

#pragma unroll
    for (int mt = 0; mt < 4; ++mt) {
        float rPT[4] = {0}, rTT[4] = {0}, rPB[4] = {0}, rTB[4] = {0};
        int til[4], bil[4];
#pragma unroll
        for (int p = 0; p < 4; ++p) {
            int il = rowBase + 16 * mt + 4 * quad + p;
            til[p] = tgA[il];
            bil[p] = btA[il];
        }
#pragma unroll
        for (int nt = 0; nt < 4; ++nt) {
#pragma unroll
            for (int p = 0; p < 4; ++p) {
                float s = acc[mt][nt][p];
                float et = __builtin_amdgcn_exp2f(c1 * s);
                float eb = __builtin_amdgcn_exp2f(c2 * s);
                bool st = (til[p] == tjv[nt]);
                bool sb = (bil[p] == bjv[nt]);
                float etp = st ? et : 0.f;
                float ebp = st ? eb : 0.f;
                float ebb = (st && sb) ? eb : 0.f;
                rTT[p] += et;
                rPT[p] += etp;
                rTB[p] += ebp;
                rPB[p] += ebb;
                cTT[nt] += et;
                cPT[nt] += etp;
                cTB[nt] += ebp;
                cPB[nt] += ebb;
            }
        }
        RED16(rPT);
        RED16(rTT);
        RED16(rPB);
        RED16(rTB);
        if ((tx16 & 3) == 0) {
            int il = rowBase + 16 * mt + 4 * quad + pOwn;
            int rep = (w & 1) * 512;
            sRowF[rep + 0 * 128 + il] = rPT[0];
            sRowF[rep + 1 * 128 + il] = rTT[0];
            sRowF[rep + 2 * 128 + il] = rPB[0];
            sRowF[rep + 3 * 128 + il] = rTB[0];
        }
    }
    if (!isDiag) {
        const bool q1 = (quad >> 1) & 1;
        const bool q0 = quad & 1;
        RED4(cPT);
        RED4(cTT);
        RED4(cPB);
        RED4(cTB);
        int cl = colBase + 16 * quad + tx16;
        int rep = (w >> 1) * 512;
        sColF[rep + 0 * 128 + cl] = cPT[0];
        sColF[rep + 1 * 128 + cl] = cTT[0];
        sColF[rep + 2 * 128 + cl] = cPB[0];
        sColF[rep + 3 * 128 + cl] = cTB[0];
    }

    // coalesced strip flush (float4 stores, no atomics; disjoint by construction)
    __syncthreads();
    if (t < 128) {
        float4 v;
        v.x = sRowF[0 * 128 + t] + sRowF[512 + 0 * 128 + t];
        v.y = sRowF[1 * 128 + t] + sRowF[512 + 1 * 128 + t];
        v.z = sRowF[2 * 128 + t] + sRowF[512 + 2 * 128 + t];
        v.w = sRowF[3 * 128 + t] + sRowF[512 + 3 * 128 + t];
        *(float4*)&strips[(size_t)(bj * NN + I + t) * 4] = v;
    } else if (!isDiag) {
        int u2 = t - 128;
        float4 v;
        v.x = sColF[0 * 128 + u2] + sColF[512 + 0 * 128 + u2];
        v.y = sColF[1 * 128 + u2] + sColF[512 + 1 * 128 + u2];
        v.z = sColF[2 * 128 + u2] + sColF[512 + 2 * 128 + u2];
        v.w = sColF[3 * 128 + u2] + sColF[512 + 3 * 128 + u2];
        *(float4*)&strips[(size_t)(bi * NN + J + u2) * 4] = v;
    }
}

// 24 blocks: strip reduce + diag correction + per-row losses + per-wave accum +
// global acc atomics + last-block final weighted sum.
__global__ __launch_bounds__(256) void k_fin(const float* __restrict__ temp,
                                             const int* __restrict__ tg,
                                             const int* __restrict__ bt,
                                             const float* __restrict__ wt,
                                             const float* __restrict__ wb,
                                             float* __restrict__ ws,
                                             float* __restrict__ out) {
    __shared__ int hh[NCLS + NCLS * NBATCH];
    __shared__ float ph[4][52];
    __shared__ int lastFlag;
    const int t = threadIdx.x;
    const int wv = t >> 6;
    if (t < NCLS + NCLS * NBATCH) hh[t] = 0;
    if (t < 52 * 4) ((float*)ph)[t] = 0.0f;
    __syncthreads();
    for (int i = t; i < NN; i += 256) {
        int c = tg[i], b = bt[i];
        atomicAdd(&hh[c], 1);
        atomicAdd(&hh[NCLS + c * NBATCH + b], 1);
    }
    __syncthreads();
    const float* strips = ws + STOFF;
    const float tc = fminf(fmaxf(temp[0], 0.1f), 1.0f);
    const float c1 = 1.4426950408889634f / tc;
    const float c2 = 2.8853900817779268f;
    {
        const int i = blockIdx.x * 256 + t;
        float pt = 0.f, tt = 0.f, pb = 0.f, tb = 0.f;
#pragma unroll 8
        for (int s = 0; s < NB; ++s) {
            float4 v = *(const float4*)&strips[(size_t)(s * NN + i) * 4];
            pt += v.x;
            tt += v.y;
            pb += v.z;
            tb += v.w;
        }
        // subtract self term (diag tiles were accumulated without exclusion)
        float s2 = ws[DOFF + i];
        float e1 = __builtin_amdgcn_exp2f(c1 * s2);
        float e2 = __builtin_amdgcn_exp2f(c2 * s2);
        pt -= e1;
        tt -= e1;
        pb -= e2;
        tb -= e2;
        int ti = tg[i], bi = bt[i];
        int cp = hh[ti];
        int cpb = hh[NCLS + ti * NBATCH + bi];
        if (cp >= 2 && (NN - cp) >= 1) {
            float loss = logf(tt / pt);  // -log(pos/tot)
            atomicAdd(&ph[wv][ti], loss);
            atomicAdd(&ph[wv][20 + ti], 1.0f);
        }
        if (cpb >= 2 && (cp - cpb) >= 1) {
            float lb = logf(tb / pb);
            atomicAdd(&ph[wv][40 + bi], 1.0f / lb);
            atomicAdd(&ph[wv][45 + bi], 1.0f);
        }
    }
    __syncthreads();
    if (t < 50) {
        float s = ph[0][t] + ph[1][t] + ph[2][t] + ph[3][t];
        atomicAdd(&ws[AOFF + t], s);
    }
    __syncthreads();
    if (t == 0) {
        __threadfence();
        lastFlag = (atomicAdd((int*)(ws + COFF), 1) == 23) ? 1 : 0;
    }
    __syncthreads();
    if (lastFlag) {
        __threadfence();
        if (t < 64) {
            const float* acc = ws + AOFF;
            float term = 0.0f;
            if (t < NCLS) {
                float cnt = acc[NCLS + t];
                if (cnt > 0.f) term = 0.9f * (acc[t] / cnt) * wt[t];
            } else if (t >= 32 && t < 32 + NBATCH) {
                int b = t - 32;
                float cnt = acc[2 * NCLS + NBATCH + b];
                if (cnt > 0.f) term = 0.1f * (acc[2 * NCLS + b] / cnt) * wb[b];
            }
#pragma unroll
            for (int m = 1; m < 64; m <<= 1) term += __shfl_xor(term, m, 64);
            if (t == 0) out[0] = term;
        }
    }
}

extern "C" void kernel_launch(void* const* d_in, const int* in_sizes, int n_in,
                              void* d_out, int out_size, void* d_ws, size_t ws_size,
                              hipStream_t stream) {
    const float* x    = (const float*)d_in[0];
    const float* temp = (const float*)d_in[1];
    const float* wt   = (const float*)d_in[2];
    const float* wb   = (const float*)d_in[3];
    const int*   tg   = (const int*)d_in[4];
    const int*   bt   = (const int*)d_in[5];
    float* out = (float*)d_out;
    float* ws = (float*)d_ws;

    k_prep<<<NN / 4, 256, 0, stream>>>(x, ws);
    k_main<<<NPAIR, 256, 0, stream>>>(temp, tg, bt, ws);
    k_fin<<<24, 256, 0, stream>>>(temp, tg, bt, wt, wb, ws, out);
}

// Round 13
// 99.812 us; speedup vs baseline: 2.0344x; 1.1611x over previous
//
#include <hip/hip_runtime.h>
#include <hip/hip_bf16.h>
#include <math.h>

#define NN 6144
#define DD 128
#define NCLS 20
#define NBATCH 5
#define NB 48                      // 6144 / 128 tile blocks per dim
#define NPAIR (NB * (NB + 1) / 2)  // 1176 upper-tri tile pairs

typedef float f32x4 __attribute__((ext_vector_type(4)));
typedef short bf16x8 __attribute__((ext_vector_type(8)));

// ws float layout:
//   ushort xnb[NN*DD]   bytes [0, 1572864)  normalized rows, bf16
//   float  stats[4*NN]  float idx SOFF: PT | TT | PB | TB
//   float  acc[50]      float idx AOFF: ls_t[20] ct_t[20] ls_b[5] cb_b[5]
//   int    counter      float idx COFF
#define SOFF (NN * DD / 2)
#define AOFF (SOFF + 4 * NN)
#define COFF (AOFF + 50)

// direct global->LDS DMA, 16 B per lane, dest = wave-uniform base + lane*16
#define GLD16(gp, lp)                                                          \
    __builtin_amdgcn_global_load_lds(                                          \
        (const __attribute__((address_space(1))) void*)(gp),                   \
        (__attribute__((address_space(3))) void*)(lp), 16, 0, 0)

// normalize rows -> bf16; blocks 0..23 zero stats; block 24 zeroes acc+counter.
__global__ __launch_bounds__(256) void k_prep(const float* __restrict__ x,
                                              float* __restrict__ ws) {
    const int t = threadIdx.x;
    if (blockIdx.x < 24) {
        float4 z = {0.f, 0.f, 0.f, 0.f};
        *(float4*)(ws + SOFF + blockIdx.x * 1024 + t * 4) = z;
    } else if (blockIdx.x == 24) {
        if (t < 51) ws[AOFF + t] = 0.0f;  // acc[50] + counter
    }
    const int lane = t & 63;
    const int row = blockIdx.x * 4 + (t >> 6);
    float2 v = *(const float2*)(x + row * DD + 2 * lane);
    float s = v.x * v.x + v.y * v.y;
#pragma unroll
    for (int m = 1; m < 64; m <<= 1) s += __shfl_xor(s, m, 64);
    float rinv = 1.0f / fmaxf(sqrtf(s), 1e-8f);
    __hip_bfloat16 h0 = __float2bfloat16(v.x * rinv);
    __hip_bfloat16 h1 = __float2bfloat16(v.y * rinv);
    ushort2 u;
    u.x = *(ushort*)&h0;
    u.y = *(ushort*)&h1;
    ushort* xnb = (ushort*)ws;
    *(ushort2*)(xnb + row * DD + 2 * lane) = u;
}

// owner-scatter reductions, scalar-expanded (SROA-friendly)
#define RED16(v)                                                      \
    {                                                                 \
        float s0 = up3 ? v[0] : v[2], k0 = up3 ? v[2] : v[0];         \
        float s1 = up3 ? v[1] : v[3], k1 = up3 ? v[3] : v[1];         \
        v[0] = k0 + __shfl_xor(s0, 8, 64);                            \
        v[1] = k1 + __shfl_xor(s1, 8, 64);                            \
        float s2 = up2 ? v[0] : v[1], k2 = up2 ? v[1] : v[0];         \
        v[0] = k2 + __shfl_xor(s2, 4, 64);                            \
        v[0] += __shfl_xor(v[0], 2, 64);                              \
        v[0] += __shfl_xor(v[0], 1, 64);                              \
    }

#define RED4(v)                                                       \
    {                                                                 \
        float s0 = q1 ? v[0] : v[2], k0 = q1 ? v[2] : v[0];           \
        float s1 = q1 ? v[1] : v[3], k1 = q1 ? v[3] : v[1];           \
        v[0] = k0 + __shfl_xor(s0, 32, 64);                           \
        v[1] = k1 + __shfl_xor(s1, 32, 64);                           \
        float s2 = q0 ? v[0] : v[1], k2 = q0 ? v[1] : v[0];           \
        v[0] = k2 + __shfl_xor(s2, 16, 64);                           \
    }

// 128x128 tile per block, upper-tri pairs. Staging via global_load_lds
// (16 B/lane DMA) into pitch-64 XOR-swizzled tiles: row r, logical chunk c
// (8 bf16) lives at physical chunk c^(r&7). Stats alias dead tile LDS;
// atomic flush (memory-side, no dirty-L2 — beats plain strip stores, R12).
// NOTE: no min-waves launch_bounds — (256,4) clamped VGPR to 64 and spilled
// ~190 MB/dispatch to scratch (round 11).
__global__ __launch_bounds__(256) void k_main(const float* __restrict__ temp,
                                              const int* __restrict__ tg,
                                              const int* __restrict__ bt,
                                              float* __restrict__ ws) {
    __shared__ __align__(16) char smem[32768];  // tA 16384 | tB 16384, pitch 128 B
    __shared__ int tgA[128], btA[128], tgB[128], btB[128];  // 2048 B

    char* tAc = smem;
    char* tBc = smem + 16384;
    float* sRowF = (float*)smem;            // alias: [2][4][128] = 4096 B
    float* sColF = (float*)(smem + 4096);   // alias: [2][4][128] = 4096 B

    const ushort* xnb = (const ushort*)ws;
    float* PT = ws + SOFF;
    float* TT = PT + NN;
    float* PB = PT + 2 * NN;
    float* TB = PT + 3 * NN;

    int bi = 0, rem = blockIdx.x;
    while (rem >= NB - bi) { rem -= NB - bi; ++bi; }
    const int bj = bi + rem;
    const int I = bi * 128, J = bj * 128;
    const bool isDiag = (bi == bj);

    const int t = threadIdx.x;
    const int w = t >> 6;
    const int lane = t & 63;
    const int tx16 = lane & 15;
    const int quad = lane >> 4;
    const int rowBase = (w >> 1) * 64;
    const int colBase = (w & 1) * 64;

    const float tc = fminf(fmaxf(temp[0], 0.1f), 1.0f);
    const float c1 = 1.4426950408889634f / tc;   // exp(s/t)   = 2^(s*c1)
    const float c2 = 2.8853900817779268f;        // exp(s/0.5) = 2^(s*c2)

    if (t < 128) { tgA[t] = tg[I + t]; btA[t] = bt[I + t]; }
    else { int u2 = t - 128; tgB[u2] = tg[J + u2]; btB[u2] = bt[J + u2]; }

    // DMA staging lane constants: lane l deposits into row R+(l>>3), physical
    // chunk l&7; so it must FETCH logical chunk (l&7)^(l>>3) of that row.
    const int rloc = lane >> 3;
    const int csw = (lane & 7) ^ rloc;

    f32x4 acc[4][4];
#pragma unroll
    for (int mt = 0; mt < 4; ++mt)
#pragma unroll
        for (int nt = 0; nt < 4; ++nt) acc[mt][nt] = (f32x4){0.f, 0.f, 0.f, 0.f};

    for (int kc = 0; kc < 2; ++kc) {
        if (kc) __syncthreads();
        {   // wave w stages A rows [32w,32w+32) and B rows likewise; 4 DMA
            // calls each side, 8 rows (1 KB contiguous LDS) per call.
            const ushort* gA = xnb + (size_t)(I + 32 * w + rloc) * DD + kc * 64 + csw * 8;
            const ushort* gB = xnb + (size_t)(J + 32 * w + rloc) * DD + kc * 64 + csw * 8;
            char* lA = tAc + (32 * w) * 128;
            char* lB = tBc + (32 * w) * 128;
#pragma unroll
            for (int q = 0; q < 4; ++q) {
                GLD16(gA + q * 8 * DD, lA + q * 1024);
                GLD16(gB + q * 8 * DD, lB + q * 1024);
            }
        }
        __syncthreads();
#pragma unroll
        for (int ks = 0; ks < 2; ++ks) {
            bf16x8 a[4], b[4];
            // logical chunk ks*4+quad, row parity tx16&7 -> physical chunk
            const int ca = (ks * 4 + quad) ^ (tx16 & 7);
#pragma unroll
            for (int mt = 0; mt < 4; ++mt)
                a[mt] = *(const bf16x8*)(tAc + (rowBase + 16 * mt + tx16) * 128 + ca * 16);
#pragma unroll
            for (int nt = 0; nt < 4; ++nt)
                b[nt] = *(const bf16x8*)(tBc + (colBase + 16 * nt + tx16) * 128 + ca * 16);
#pragma unroll
            for (int mt = 0; mt < 4; ++mt)
#pragma unroll
                for (int nt = 0; nt < 4; ++nt)
                    acc[mt][nt] = __builtin_amdgcn_mfma_f32_16x16x32_bf16(
                        a[mt], b[nt], acc[mt][nt], 0, 0, 0);
        }
    }

    // tiles dead from here; stats alias onto the same LDS
    __syncthreads();

    float cPT[4] = {0}, cTT[4] = {0}, cPB[4] = {0}, cTB[4] = {0};
    int tjv[4], bjv[4];
#pragma unroll
    for (int nt = 0; nt < 4; ++nt) {
        int jl = colBase + 16 * nt + tx16;
        tjv[nt] = tgB[jl];
        bjv[nt] = btB[jl];
    }
    const bool up3 = (tx16 >> 3) & 1;
    const bool up2 = (tx16 >> 2) & 1;
    const int pOwn = tx16 >> 2;

#pragma unroll
    for (int mt = 0; mt < 4; ++mt) {
        float rPT[4] = {0}, rTT[4] = {0}, rPB[4] = {0}, rTB[4] = {0};
        int til[4], bil[4];
#pragma unroll
        for (int p = 0; p < 4; ++p) {
            int il = rowBase + 16 * mt + 4 * quad + p;
            til[p] = tgA[il];
            bil[p] = btA[il];
        }
        if (isDiag) {
#pragma unroll
            for (int nt = 0; nt < 4; ++nt) {
                const int jl = colBase + 16 * nt + tx16;
#pragma unroll
                for (int p = 0; p < 4; ++p) {
                    const int il = rowBase + 16 * mt + 4 * quad + p;
                    float s = acc[mt][nt][p];
                    float et = __builtin_amdgcn_exp2f(c1 * s);
                    float eb = __builtin_amdgcn_exp2f(c2 * s);
                    bool nd = (il != jl);
                    bool st = (til[p] == tjv[nt]) && nd;
                    bool sb = (bil[p] == bjv[nt]);
                    rTT[p] += nd ? et : 0.f;
                    rPT[p] += st ? et : 0.f;
                    rTB[p] += st ? eb : 0.f;
                    rPB[p] += (st && sb) ? eb : 0.f;
                }
            }
        } else {
#pragma unroll
            for (int nt = 0; nt < 4; ++nt) {
#pragma unroll
                for (int p = 0; p < 4; ++p) {
                    float s = acc[mt][nt][p];
                    float et = __builtin_amdgcn_exp2f(c1 * s);
                    float eb = __builtin_amdgcn_exp2f(c2 * s);
                    bool st = (til[p] == tjv[nt]);
                    bool sb = (bil[p] == bjv[nt]);
                    float etp = st ? et : 0.f;
                    float ebp = st ? eb : 0.f;
                    float ebb = (st && sb) ? eb : 0.f;
                    rTT[p] += et;
                    rPT[p] += etp;
                    rTB[p] += ebp;
                    rPB[p] += ebb;
                    cTT[nt] += et;
                    cPT[nt] += etp;
                    cTB[nt] += ebp;
                    cPB[nt] += ebb;
                }
            }
        }
        RED16(rPT);
        RED16(rTT);
        RED16(rPB);
        RED16(rTB);
        if ((tx16 & 3) == 0) {
            int il = rowBase + 16 * mt + 4 * quad + pOwn;
            int rep = (w & 1) * 512;
            sRowF[rep + 0 * 128 + il] = rPT[0];
            sRowF[rep + 1 * 128 + il] = rTT[0];
            sRowF[rep + 2 * 128 + il] = rPB[0];
            sRowF[rep + 3 * 128 + il] = rTB[0];
        }
    }
    if (!isDiag) {
        const bool q1 = (quad >> 1) & 1;
        const bool q0 = quad & 1;
        RED4(cPT);
        RED4(cTT);
        RED4(cPB);
        RED4(cTB);
        int cl = colBase + 16 * quad + tx16;
        int rep = (w >> 1) * 512;
        sColF[rep + 0 * 128 + cl] = cPT[0];
        sColF[rep + 1 * 128 + cl] = cTT[0];
        sColF[rep + 2 * 128 + cl] = cPB[0];
        sColF[rep + 3 * 128 + cl] = cTB[0];
    }

    // coalesced global-atomic flush (memory-side cache, no dirty L2)
    __syncthreads();
    if (t < 128) {
        int gi = I + t;
        atomicAdd(&PT[gi], sRowF[0 * 128 + t] + sRowF[512 + 0 * 128 + t]);
        atomicAdd(&TT[gi], sRowF[1 * 128 + t] + sRowF[512 + 1 * 128 + t]);
        atomicAdd(&PB[gi], sRowF[2 * 128 + t] + sRowF[512 + 2 * 128 + t]);
        atomicAdd(&TB[gi], sRowF[3 * 128 + t] + sRowF[512 + 3 * 128 + t]);
    } else if (!isDiag) {
        int u2 = t - 128;
        int gj = J + u2;
        atomicAdd(&PT[gj], sColF[0 * 128 + u2] + sColF[512 + 0 * 128 + u2]);
        atomicAdd(&TT[gj], sColF[1 * 128 + u2] + sColF[512 + 1 * 128 + u2]);
        atomicAdd(&PB[gj], sColF[2 * 128 + u2] + sColF[512 + 2 * 128 + u2]);
        atomicAdd(&TB[gj], sColF[3 * 128 + u2] + sColF[512 + 3 * 128 + u2]);
    }
}

// 24 blocks: per-block LDS histogram, one row/thread losses, per-wave accum,
// global acc atomics, last-block-done final weighted sum.
__global__ __launch_bounds__(256) void k_fin(const int* __restrict__ tg,
                                             const int* __restrict__ bt,
                                             const float* __restrict__ wt,
                                             const float* __restrict__ wb,
                                             float* __restrict__ ws,
                                             float* __restrict__ out) {
    __shared__ int hh[NCLS + NCLS * NBATCH];
    __shared__ float ph[4][52];
    __shared__ int lastFlag;
    const int t = threadIdx.x;
    const int wv = t >> 6;
    if (t < NCLS + NCLS * NBATCH) hh[t] = 0;
    if (t < 52 * 4) ((float*)ph)[t] = 0.0f;
    __syncthreads();
    for (int i = t; i < NN; i += 256) {
        int c = tg[i], b = bt[i];
        atomicAdd(&hh[c], 1);
        atomicAdd(&hh[NCLS + c * NBATCH + b], 1);
    }
    __syncthreads();
    const float* PT = ws + SOFF;
    const float* TT = PT + NN;
    const float* PB = PT + 2 * NN;
    const float* TB = PT + 3 * NN;
    {
        const int i = blockIdx.x * 256 + t;
        float pt = PT[i], tt = TT[i], pb = PB[i], tb = TB[i];
        int ti = tg[i], bi = bt[i];
        int cp = hh[ti];
        int cpb = hh[NCLS + ti * NBATCH + bi];
        if (cp >= 2 && (NN - cp) >= 1) {
            float loss = logf(tt / pt);  // -log(pos/tot)
            atomicAdd(&ph[wv][ti], loss);
            atomicAdd(&ph[wv][20 + ti], 1.0f);
        }
        if (cpb >= 2 && (cp - cpb) >= 1) {
            float lb = logf(tb / pb);
            atomicAdd(&ph[wv][40 + bi], 1.0f / lb);
            atomicAdd(&ph[wv][45 + bi], 1.0f);
        }
    }
    __syncthreads();
    if (t < 50) {
        float s = ph[0][t] + ph[1][t] + ph[2][t] + ph[3][t];
        atomicAdd(&ws[AOFF + t], s);
    }
    __syncthreads();
    if (t == 0) {
        __threadfence();
        lastFlag = (atomicAdd((int*)(ws + COFF), 1) == 23) ? 1 : 0;
    }
    __syncthreads();
    if (lastFlag) {
        __threadfence();
        if (t < 64) {
            const float* acc = ws + AOFF;
            float term = 0.0f;
            if (t < NCLS) {
                float cnt = acc[NCLS + t];
                if (cnt > 0.f) term = 0.9f * (acc[t] / cnt) * wt[t];
            } else if (t >= 32 && t < 32 + NBATCH) {
                int b = t - 32;
                float cnt = acc[2 * NCLS + NBATCH + b];
                if (cnt > 0.f) term = 0.1f * (acc[2 * NCLS + b] / cnt) * wb[b];
            }
#pragma unroll
            for (int m = 1; m < 64; m <<= 1) term += __shfl_xor(term, m, 64);
            if (t == 0) out[0] = term;
        }
    }
}

extern "C" void kernel_launch(void* const* d_in, const int* in_sizes, int n_in,
                              void* d_out, int out_size, void* d_ws, size_t ws_size,
                              hipStream_t stream) {
    const float* x    = (const float*)d_in[0];
    const float* temp = (const float*)d_in[1];
    const float* wt   = (const float*)d_in[2];
    const float* wb   = (const float*)d_in[3];
    const int*   tg   = (const int*)d_in[4];
    const int*   bt   = (const int*)d_in[5];
    float* out = (float*)d_out;
    float* ws = (float*)d_ws;

    k_prep<<<NN / 4, 256, 0, stream>>>(x, ws);
    k_main<<<NPAIR, 256, 0, stream>>>(temp, tg, bt, ws);
    k_fin<<<24, 256, 0, stream>>>(tg, bt, wt, wb, ws, out);
}